// Round 1
// baseline (347.298 us; speedup 1.0000x reference)
//
#include <hip/hip_runtime.h>
#include <hip/hip_bf16.h>
#include <math.h>

// Problem constants
#define N_ROUTES 7
#define PC_DIM   512
#define MC_DIM   128
#define KCLS     25
#define BATCH    4096

#define ROW_IN   (N_ROUTES * PC_DIM)          // 3584 elems per batch row of pose
#define JDIM     (KCLS * MC_DIM)              // 3200 vote cols per route
#define VOTE_B   (N_ROUTES * JDIM)            // 22400 vote elems per batch elem

typedef __attribute__((ext_vector_type(8))) _Float16 half8;
typedef __attribute__((ext_vector_type(4))) float f32x4;

__device__ inline ushort f2h(float f) {
    _Float16 h = (_Float16)f;
    return __builtin_bit_cast(ushort, h);
}

__device__ inline float2 h2f2(uint u) {
    union { uint x; _Float16 h[2]; } c; c.x = u;
    return make_float2((float)c.h[0], (float)c.h[1]);
}

__device__ inline void load_lds16(const void* g, void* l) {
    __builtin_amdgcn_global_load_lds(
        (const __attribute__((address_space(1))) void*)g,
        (__attribute__((address_space(3))) void*)l, 16, 0, 0);
}

// ---------------- conversion kernels ----------------
__global__ __launch_bounds__(256) void conv_pose(const float* __restrict__ p,
                                                 ushort* __restrict__ pb, int n8) {
    int i = blockIdx.x * 256 + threadIdx.x;
    if (i >= n8) return;
    const float4* s = (const float4*)p + (size_t)i * 2;
    float4 a = s[0], b = s[1];
    ushort t[8];
    t[0]=f2h(a.x); t[1]=f2h(a.y); t[2]=f2h(a.z); t[3]=f2h(a.w);
    t[4]=f2h(b.x); t[5]=f2h(b.y); t[6]=f2h(b.z); t[7]=f2h(b.w);
    *(uint4*)(pb + (size_t)i * 8) = *(uint4*)t;
}

// w fp32 [7][512][3200] -> wt fp16 [7][3200][512] (transposed per route)
__global__ __launch_bounds__(256) void conv_w(const float* __restrict__ w,
                                              ushort* __restrict__ wt) {
    __shared__ float t[32][33];
    const int j0 = blockIdx.x * 32, d0 = blockIdx.y * 32, r = blockIdx.z;
    const int c = threadIdx.x & 31, rr = threadIdx.x >> 5;
    const float* wp = w + (size_t)r * PC_DIM * JDIM;
#pragma unroll
    for (int i = 0; i < 4; i++)
        t[rr + i * 8][c] = wp[(size_t)(d0 + rr + i * 8) * JDIM + j0 + c];
    __syncthreads();
    ushort* op = wt + (size_t)r * JDIM * PC_DIM;
#pragma unroll
    for (int i = 0; i < 4; i++)
        op[(size_t)(j0 + rr + i * 8) * PC_DIM + d0 + c] = f2h(t[c][rr + i * 8]);
}

// ---------------- Kernel 1: MFMA vote GEMM (fp16 in, fp16 out) ----------------
// r8 rewrite: 256x256 tile, BK=32, 512 threads = 8 waves (2M x 4N), wave tile
// 128x64 (template MFMA:ds ratio 32:12 per K-tile). 4-deep LDS rotation
// (4 x 32KB = 128KB) with counted s_waitcnt vmcnt(8) -- loads for 3 future
// K-tiles stay in flight across raw s_barriers (T3+T4). setprio(1) around the
// 16-MFMA clusters (T5). XOR swizzle: chunk c ^ ((row>>1)&3), linear LDS dest +
// pre-swizzled global source (both-sides involution). N=3200 -> 13 jTiles of
// 256 with masked tail; B row reads clamped in-bounds.

#define BAR() do { __builtin_amdgcn_sched_barrier(0); \
                   __builtin_amdgcn_s_barrier(); \
                   __builtin_amdgcn_sched_barrier(0); } while (0)
#define WAIT_LGKM0() do { asm volatile("s_waitcnt lgkmcnt(0)" ::: "memory"); \
                          __builtin_amdgcn_sched_barrier(0); } while (0)
#define WAIT_VM(n) do { asm volatile("s_waitcnt vmcnt(" #n ")" ::: "memory"); } while (0)

__global__ __launch_bounds__(512, 2) void vote_gemm_mfma(
        const ushort* __restrict__ poseb,  // [rows][3584] fp16
        const ushort* __restrict__ wt,     // [7][3200][512] fp16
        ushort* __restrict__ vote,         // [rows][7][3200] fp16
        int rows) {
    __shared__ __align__(16) char smem[131072];   // 4 bufs x (A 16KB | B 16KB)

    int route, rowTile, jTile;
    if (gridDim.x == 1456) {               // full batch: 16 rowTiles x 7 x 13
        const int x = blockIdx.x & 7;      // XCD id (perf heuristic only)
        const int g = blockIdx.x >> 3;     // 0..181
        const int q = g / 91;              // 0..1  (91 = 7*13)
        const int rem = g - q * 91;
        route = rem / 13;
        jTile = rem - route * 13;
        rowTile = x * 2 + q;               // per-XCD: 2 rowTiles, A slab L2-hot
    } else {
        rowTile = blockIdx.x / 91;
        const int rem = blockIdx.x - rowTile * 91;
        route = rem / 13;
        jTile = rem - route * 13;
    }
    const int b0 = rowTile * 256;
    const int j0 = jTile * 256;

    const int tid = threadIdx.x;
    const int l = tid & 63, w = tid >> 6;
    const int wm = w >> 2, wn = w & 3;     // 2 M-waves x 4 N-waves
    const int lm = l & 15, q4 = l >> 4;
    const int xr = (l >> 1) & 3;           // == ((row>>1)&3) for row = 16k + lm

    const ushort* Aptr = poseb + (size_t)route * PC_DIM;
    const ushort* Bptr = wt + (size_t)route * JDIM * PC_DIM;

    // Per-thread staging source offsets (elements). Chunk f covers 8 fp16:
    // row = f>>2, c = f&3, pre-swizzled source col-group qg = c ^ ((row>>1)&3).
    uint aof0, aof1, bof0, bof1;
    {
        int f, row, c, qg, ga, jr;
        f = tid;        row = f >> 2; c = f & 3; qg = c ^ ((row >> 1) & 3);
        ga = b0 + row; if (ga >= rows) ga = rows - 1;
        aof0 = (uint)ga * ROW_IN + qg * 8;
        jr = j0 + row; if (jr >= JDIM) jr = JDIM - 1;
        bof0 = (uint)jr * PC_DIM + qg * 8;
        f = tid + 512;  row = f >> 2; c = f & 3; qg = c ^ ((row >> 1) & 3);
        ga = b0 + row; if (ga >= rows) ga = rows - 1;
        aof1 = (uint)ga * ROW_IN + qg * 8;
        jr = j0 + row; if (jr >= JDIM) jr = JDIM - 1;
        bof1 = (uint)jr * PC_DIM + qg * 8;
    }

    // LDS byte offsets of this lane's fragments (swizzled read side).
    const int aBase = ((wm * 128 + lm) * 4 + (q4 ^ xr)) * 16;           // + mt*1024
    const int bBase = 16384 + ((wn * 64 + lm) * 4 + (q4 ^ xr)) * 16;    // + nt*1024

    f32x4 acc[8][4] = {};

#define STAGE_A(kt) do { \
        char* d_ = smem + (((kt) & 3) * 32768); \
        load_lds16(Aptr + aof0 + (kt) * 32, d_ + (size_t)tid * 16); \
        load_lds16(Aptr + aof1 + (kt) * 32, d_ + (size_t)(tid + 512) * 16); \
    } while (0)
#define STAGE_B(kt) do { \
        char* d_ = smem + (((kt) & 3) * 32768) + 16384; \
        load_lds16(Bptr + bof0 + (kt) * 32, d_ + (size_t)tid * 16); \
        load_lds16(Bptr + bof1 + (kt) * 32, d_ + (size_t)(tid + 512) * 16); \
    } while (0)

    // Prologue: tiles 0,1,2 staged (12 loads/thread); wait tile0 (leave 8).
    STAGE_A(0); STAGE_B(0);
    STAGE_A(1); STAGE_B(1);
    STAGE_A(2); STAGE_B(2);
    WAIT_VM(8);
    BAR();

    half8 af[4], bf[4];

    // One K-tile: 2 phases. P0: read B(4)+A(mt0-3), issue A-stage(t+3), 16 MFMA.
    // P1: read A(mt4-7), issue B-stage(t+3), 16 MFMA, counted vmcnt, barrier.
#define TILE(t, SA, SB, VM) do { \
        const char* bp_ = smem + (((t) & 3) * 32768); \
        _Pragma("unroll") for (int nt = 0; nt < 4; nt++) \
            bf[nt] = *(const half8*)(bp_ + bBase + nt * 1024); \
        _Pragma("unroll") for (int mt = 0; mt < 4; mt++) \
            af[mt] = *(const half8*)(bp_ + aBase + mt * 1024); \
        SA; \
        BAR(); \
        WAIT_LGKM0(); \
        __builtin_amdgcn_s_setprio(1); \
        _Pragma("unroll") for (int mt = 0; mt < 4; mt++) \
        _Pragma("unroll") for (int nt = 0; nt < 4; nt++) \
            acc[mt][nt] = __builtin_amdgcn_mfma_f32_16x16x32_f16( \
                af[mt], bf[nt], acc[mt][nt], 0, 0, 0); \
        __builtin_amdgcn_s_setprio(0); \
        BAR(); \
        _Pragma("unroll") for (int mt = 0; mt < 4; mt++) \
            af[mt] = *(const half8*)(bp_ + aBase + (mt + 4) * 1024); \
        SB; \
        BAR(); \
        WAIT_LGKM0(); \
        __builtin_amdgcn_s_setprio(1); \
        _Pragma("unroll") for (int mt = 0; mt < 4; mt++) \
        _Pragma("unroll") for (int nt = 0; nt < 4; nt++) \
            acc[mt + 4][nt] = __builtin_amdgcn_mfma_f32_16x16x32_f16( \
                af[mt], bf[nt], acc[mt + 4][nt], 0, 0, 0); \
        __builtin_amdgcn_s_setprio(0); \
        VM; \
        BAR(); \
    } while (0)

    for (int t = 0; t < 13; ++t)
        TILE(t, STAGE_A(t + 3), STAGE_B(t + 3), WAIT_VM(8));
    TILE(13, , , WAIT_VM(4));
    TILE(14, , , WAIT_VM(0));
    TILE(15, , , );

    // Epilogue: per-wave LDS transpose (region reuse after final barrier; each
    // wave private 16x68 floats -> no cross-wave sync needed, wave-local lgkm).
    float* ep = (float*)smem + w * 1088;   // 16*68 floats per wave
    const int erow = l >> 2, ec0 = (l & 3) * 16;
    const int jv = j0 + wn * 64;
    const bool jok = jv < JDIM;
#pragma unroll
    for (int mt = 0; mt < 8; mt++) {
#pragma unroll
        for (int nt = 0; nt < 4; nt++)
#pragma unroll
            for (int i = 0; i < 4; i++)
                ep[(q4 * 4 + i) * 68 + nt * 16 + lm] = acc[mt][nt][i];
        asm volatile("s_waitcnt lgkmcnt(0)" ::: "memory");
        const int grow = b0 + wm * 128 + mt * 16 + erow;
        if (jok && grow < rows) {
            ushort t16[16];
#pragma unroll
            for (int t8 = 0; t8 < 4; t8++) {
                float4 v = *(float4*)&ep[erow * 68 + ec0 + t8 * 4];
                t16[t8*4+0]=f2h(v.x); t16[t8*4+1]=f2h(v.y);
                t16[t8*4+2]=f2h(v.z); t16[t8*4+3]=f2h(v.w);
            }
            ushort* dst = vote + (size_t)grow * VOTE_B + route * JDIM + jv + ec0;
            ((uint4*)dst)[0] = ((uint4*)t16)[0];
            ((uint4*)dst)[1] = ((uint4*)t16)[1];
        }
        asm volatile("s_waitcnt lgkmcnt(0)" ::: "memory");
    }
}

// ---------------- Kernel 2: fused routing ----------------
// Block = one batch elem, 448 threads (7 waves). Lane decomposition:
//   sub = l&15 -> v-dims [8*sub, 8*sub+8);  mg = l>>4;  m = wv + 7*mg (28 slots, 25 valid).
// Votes unpacked ONCE to 56 fp32 regs (VALU-throughput-bound kernel: the 5-pass
// fp16 re-unpack was ~35% of all VALU issue). Reductions: 4-step shfl over 16 lanes.
__global__ __launch_bounds__(448) void routing_kernel(
        const ushort* __restrict__ vote16,  // [chunk][7][25][128] fp16
        const float* __restrict__ act,      // (pre-offset)
        const float* __restrict__ gamma,
        const float* __restrict__ beta,
        const float* __restrict__ emb,      // [25,128]
        const float* __restrict__ bias,     // [25]
        float* __restrict__ out_logits,
        float* __restrict__ out_act,
        float* __restrict__ out_coef) {
    const int b = blockIdx.x;
    __shared__ float coef_s[N_ROUTES * KCLS];
    __shared__ float act_s[8];

    const int tid = threadIdx.x, l = tid & 63, wv = tid >> 6;   // 7 waves
    const int sub = l & 15, mg = l >> 4;
    const int m = wv + 7 * mg;                // 0..27
    const bool mv = (m < KCLS);

    if (tid < N_ROUTES) {
        float a = act[(size_t)b * N_ROUTES + tid];
        act_s[tid] = a;
        out_act[(size_t)b * N_ROUTES + tid] = a;
    }

    // Load votes (coalesced 16B) and unpack to fp32 ONCE.
    float vf[N_ROUTES][8];
    if (mv) {
        const uint4* vb = (const uint4*)(vote16 + (size_t)b * VOTE_B);  // n*400 + m*16 + sub
#pragma unroll
        for (int n = 0; n < N_ROUTES; n++) {
            uint4 q = vb[n * 400 + m * 16 + sub];
            float2 f0 = h2f2(q.x), f1 = h2f2(q.y), f2 = h2f2(q.z), f3 = h2f2(q.w);
            vf[n][0] = f0.x; vf[n][1] = f0.y; vf[n][2] = f1.x; vf[n][3] = f1.y;
            vf[n][4] = f2.x; vf[n][5] = f2.y; vf[n][6] = f3.x; vf[n][7] = f3.y;
        }
    } else {
#pragma unroll
        for (int n = 0; n < N_ROUTES; n++)
#pragma unroll
            for (int j = 0; j < 8; j++) vf[n][j] = 0.f;
    }
    const int mc = mv ? m : 24;

    float g[8], be[8];
    *(float4*)(g)      = *(const float4*)(gamma + 8 * sub);
    *(float4*)(g + 4)  = *(const float4*)(gamma + 8 * sub + 4);
    *(float4*)(be)     = *(const float4*)(beta  + 8 * sub);
    *(float4*)(be + 4) = *(const float4*)(beta  + 8 * sub + 4);
    __syncthreads();   // act_s ready

    const float scale = 0.088388347648318447f;    // 1/sqrt(128)
    float pose[8];

    auto update = [&](bool first) {
        float r[8];
#pragma unroll
        for (int j = 0; j < 8; j++) r[j] = 0.f;
#pragma unroll
        for (int n = 0; n < N_ROUTES; n++) {
            float c = first ? (act_s[n] * 0.04f) : (coef_s[n * KCLS + mc] * act_s[n]);
#pragma unroll
            for (int j = 0; j < 8; j++) r[j] += c * vf[n][j];
        }
        float S = 0.f, Q = 0.f;
#pragma unroll
        for (int j = 0; j < 8; j++) { S += r[j]; Q += r[j] * r[j]; }
#pragma unroll
        for (int o = 8; o; o >>= 1) {
            S += __shfl_xor(S, o);
            Q += __shfl_xor(Q, o);
        }
        float mean = S * 0.0078125f;
        float var  = Q * 0.0078125f - mean * mean;
        float rs   = rsqrtf(var + 1e-5f);
#pragma unroll
        for (int j = 0; j < 8; j++) pose[j] = (r[j] - mean) * rs * g[j] + be[j];
    };

    update(true);
    __syncthreads();

    const int sgrp = tid >> 5, slane = tid & 31;   // 14 x 32-lane groups for softmax

    for (int it = 1; it < 3; it++) {
        // agreement: d[n] = <vote[n][m], pose[m]>
        float d[N_ROUTES];
#pragma unroll
        for (int n = 0; n < N_ROUTES; n++) {
            float t = 0.f;
#pragma unroll
            for (int j = 0; j < 8; j++) t += vf[n][j] * pose[j];
            d[n] = t;
        }
#pragma unroll
        for (int o = 8; o; o >>= 1)
#pragma unroll
            for (int n = 0; n < N_ROUTES; n++) d[n] += __shfl_xor(d[n], o);
        if (sub == 0 && mv) {
#pragma unroll
            for (int n = 0; n < N_ROUTES; n++) coef_s[n * KCLS + m] = d[n] * scale;
        }
        __syncthreads();
        // parallel softmax: group sgrp = route, lane slane = m
        if (sgrp < N_ROUTES) {
            float c = (slane < KCLS) ? coef_s[sgrp * KCLS + slane] : -1e30f;
            float mx = c;
#pragma unroll
            for (int o = 16; o; o >>= 1) mx = fmaxf(mx, __shfl_xor(mx, o, 32));
            float e = (slane < KCLS) ? expf(c - mx) : 0.f;
            float s = e;
#pragma unroll
            for (int o = 16; o; o >>= 1) s += __shfl_xor(s, o, 32);
            if (slane < KCLS) coef_s[sgrp * KCLS + slane] = e / s;
        }
        __syncthreads();
        update(false);
        if (it == 1) __syncthreads();   // coef_s reads done before next agree overwrites
    }

    // logits
    float e[8];
    *(float4*)(e)     = *(const float4*)(emb + mc * MC_DIM + 8 * sub);
    *(float4*)(e + 4) = *(const float4*)(emb + mc * MC_DIM + 8 * sub + 4);
    float dd = 0.f;
#pragma unroll
    for (int j = 0; j < 8; j++) dd += pose[j] * e[j];
#pragma unroll
    for (int o = 8; o; o >>= 1) dd += __shfl_xor(dd, o);
    if (sub == 0 && mv) out_logits[(size_t)b * KCLS + m] = dd + bias[m];

    if (tid < N_ROUTES * KCLS)
        out_coef[(size_t)b * (N_ROUTES * KCLS) + tid] = coef_s[tid];
}

// ---------------- launch ----------------
extern "C" void kernel_launch(void* const* d_in, const int* in_sizes, int n_in,
                              void* d_out, int out_size, void* d_ws, size_t ws_size,
                              hipStream_t stream) {
    const float* pose  = (const float*)d_in[0];
    const float* act   = (const float*)d_in[1];
    const float* w     = (const float*)d_in[2];
    const float* gamma = (const float*)d_in[3];
    const float* beta  = (const float*)d_in[4];
    const float* emb   = (const float*)d_in[5];
    const float* bias  = (const float*)d_in[6];

    float* out        = (float*)d_out;
    float* out_logits = out;
    float* out_act    = out + BATCH * KCLS;
    float* out_coef   = out + BATCH * KCLS + BATCH * N_ROUTES;

    // workspace: wt fp16 | poseb fp16 | vote fp16 (chunked)
    const size_t wt_bytes    = (size_t)N_ROUTES * JDIM * PC_DIM * 2;
    const size_t poseb_bytes = (size_t)BATCH * ROW_IN * 2;
    ushort* wt    = (ushort*)d_ws;
    ushort* poseb = (ushort*)((char*)d_ws + wt_bytes);
    ushort* voteh = (ushort*)((char*)d_ws + wt_bytes + poseb_bytes);

    size_t rem = ws_size > wt_bytes + poseb_bytes ? ws_size - wt_bytes - poseb_bytes : 0;
    size_t cap = rem / ((size_t)VOTE_B * 2);
    int chunk;
    if (cap >= (size_t)BATCH)  chunk = BATCH;
    else if (cap >= 128)       chunk = (int)(cap & ~(size_t)127);
    else                       chunk = (int)(cap > 0 ? cap : 1);

    conv_w<<<dim3(JDIM / 32, PC_DIM / 32, N_ROUTES), 256, 0, stream>>>(w, wt);
    const int n8 = BATCH * ROW_IN / 8;
    conv_pose<<<(n8 + 255) / 256, 256, 0, stream>>>(pose, poseb, n8);

    for (int b0 = 0; b0 < BATCH; b0 += chunk) {
        int rows = BATCH - b0 < chunk ? BATCH - b0 : chunk;
        int nRowTiles = (rows + 255) / 256;
        vote_gemm_mfma<<<nRowTiles * N_ROUTES * 13, 512, 0, stream>>>(
            poseb + (size_t)b0 * ROW_IN, wt, voteh, rows);
        routing_kernel<<<rows, 448, 0, stream>>>(
            voteh,
            act + (size_t)b0 * N_ROUTES,
            gamma, beta, emb, bias,
            out_logits + (size_t)b0 * KCLS,
            out_act    + (size_t)b0 * N_ROUTES,
            out_coef   + (size_t)b0 * N_ROUTES * KCLS);
    }
}